// Round 6
// baseline (175.427 us; speedup 1.0000x reference)
//
#include <hip/hip_runtime.h>
#include <cstdint>

// HebbFF T=128,B=8,N=512,D=256,O=1.
// R6: part2 reformulated via Gram matrix. z(t) = z0(t) + sum_{s<t} W[t][s] u(s),
// u = sigmoid(z), W[t][s] = eta_a * lam_a^{t-1-s} * (h_m(s).h_m(t)), z0 = w_add@h_m + b_add.
// Kernels: np_part1 (h_mult chain, emits h_pair packed layout) -> np_mid (Base GEMM
// + Gram, fused by block role) -> np_scan (4096 independent scalar chains, tiled 16,
// column-form triangle) -> np_final (w_final dot + sigmoid).
// Fallback to the R5 3-kernel path if ws_size < 4.72 MB.

#define T_ 128
#define B_ 8
#define N_ 512
#define D_ 256
#define NTHREADS 512
#define CH 16
#define NC (T_ / CH)

// new-path ws layout (floats)
#define HP_OFF 0                       // h_pair [T/2*B][N][2] : 524288 fl
#define Z0_OFF 524288                  // z0 / u [T*B][N]      : 524288 fl
#define WS_OFF 1048576                 // W_scan [B][T][T]     : 131072 fl
#define WS_NEED ((size_t)(1048576 + 131072) * 4)

// old-path (fallback) layout
#define HOFF (T_ * B_ * N_)

typedef float v2f __attribute__((ext_vector_type(2)));

__device__ __forceinline__ v2f v2(float s) { v2f r; r.x = s; r.y = s; return r; }
__device__ __forceinline__ v2f mk2(float a, float b) { v2f r; r.x = a; r.y = b; return r; }

__device__ __forceinline__ void load_lds16(const float* g, float* l) {
  __builtin_amdgcn_global_load_lds(
      (const __attribute__((address_space(1))) uint32_t*)(const void*)g,
      (__attribute__((address_space(3))) uint32_t*)(void*)l, 16, 0, 0);
}

__device__ __forceinline__ float dpp_wave_sum(float v) {
#define UPD(ctrl)                                                              \
  v += __int_as_float(                                                         \
      __builtin_amdgcn_update_dpp(0, __float_as_int(v), ctrl, 0xf, 0xf, true))
  UPD(0x111); UPD(0x112); UPD(0x114); UPD(0x118); UPD(0x142); UPD(0x143);
#undef UPD
  return __int_as_float(__builtin_amdgcn_readlane(__float_as_int(v), 63));
}
__device__ __forceinline__ float sigmoid_f(float z) {
  return __builtin_amdgcn_rcpf(1.f + __expf(-z));
}
__device__ __forceinline__ float tanh_f(float z) {
  return 1.f - 2.f * __builtin_amdgcn_rcpf(1.f + __expf(2.f * z));
}

// ================= new path =================

// ---- part1: h_mult/A_mult chain; emits h_pair[(t>>1)*B+b][n][2] ----
__global__ void __launch_bounds__(NTHREADS, 2)
np_part1(const float* __restrict__ x, const float* __restrict__ w_mult,
         const float* __restrict__ b_mult, const float* __restrict__ p_lm,
         const float* __restrict__ p_em, float* __restrict__ ws) {
  const int g = blockIdx.x & 7, sub = blockIdx.x >> 3;
  const int wave = threadIdx.x >> 6, lane = threadIdx.x & 63;
  const int n0 = (sub * 8 + wave) * 2;
  __shared__ float xs[2][CH][D_];

  const float lam = sigmoid_f(p_lm[0]);
  const float eta = p_em[0];
  const v2f lam2 = v2(lam), klam2 = v2(1.f - lam);

  v2f wm[2][2], Bm[2][2];
  float bm[2];
#pragma unroll
  for (int r = 0; r < 2; ++r) {
    bm[r] = b_mult[n0 + r];
#pragma unroll
    for (int c = 0; c < 2; ++c) {
      wm[r][c] = *(const v2f*)&w_mult[(n0 + r) * D_ + c * 128 + 2 * lane];
      Bm[r][c] = v2(1.f);
    }
  }

  auto issue_stage = [&](int c) {
#pragma unroll
    for (int k = 0; k < 2; ++k) {
      const int row = k * 8 + wave;
      load_lds16(&x[((c * CH + row) * B_ + g) * D_ + 4 * lane],
                 &xs[c & 1][row][0]);
    }
  };
  issue_stage(0);
  __syncthreads();

  float* hp = ws + HP_OFF;
  v2f xv[2][2];
  auto ldx = [&](int buf, int cb, int tl) {
    xv[buf][0] = *(const v2f*)&xs[cb][tl][2 * lane];
    xv[buf][1] = *(const v2f*)&xs[cb][tl][128 + 2 * lane];
  };

  float ph0 = 0.f, ph1 = 0.f;
  for (int c = 0; c < NC; ++c) {
    if (c + 1 < NC) issue_stage(c + 1);
    const int cb = c & 1;
    ldx(0, cb, 0);
#pragma unroll
    for (int tl = 0; tl < CH; ++tl) {
      const int buf = tl & 1;
      if (tl + 1 < CH) ldx(buf ^ 1, cb, tl + 1);
      float hmv[2];
#pragma unroll
      for (int r = 0; r < 2; ++r) {
        v2f a = wm[r][0] * xv[buf][0] * Bm[r][0];
        a = __builtin_elementwise_fma(wm[r][1] * xv[buf][1], Bm[r][1], a);
        const float z = dpp_wave_sum(a.x + a.y) + bm[r];
        const float hm = tanh_f(z);
        hmv[r] = hm;
        const v2f c2 = v2(eta * hm);
#pragma unroll
        for (int cc = 0; cc < 2; ++cc) {
          v2f inner = __builtin_elementwise_fma(c2, xv[buf][cc], klam2);
          Bm[r][cc] = __builtin_elementwise_fma(lam2, Bm[r][cc], inner);
        }
      }
      if (tl & 1) {
        if (lane == 0) {
          const int t2 = (c * CH + tl) >> 1;
          *(float4*)(hp + ((t2 * B_ + g) * N_ + n0) * 2) =
              make_float4(ph0, hmv[0], ph1, hmv[1]);
        }
      } else {
        ph0 = hmv[0];
        ph1 = hmv[1];
      }
    }
    __syncthreads();
  }
}

// ---- mid: blocks 0..127 = Base GEMM (z0 = h@w_add^T + b_add),
//          blocks 128..191 = Gram -> W_scan[b][t][s] ----
__global__ void __launch_bounds__(NTHREADS, 2)
np_mid(const float* __restrict__ w_add, const float* __restrict__ b_add,
       const float* __restrict__ p_la, const float* __restrict__ p_ea,
       float* __restrict__ ws) {
  __shared__ float hl[8192];  // 32 KB
  const int tid = threadIdx.x;
  const int wave = tid >> 6, lane = tid & 63;
  const float* hp = ws + HP_OFF;
  float* z0 = ws + Z0_OFF;
  float* Wsc = ws + WS_OFF;
  const float lam = sigmoid_f(p_la[0]);
  const float eta = p_ea[0];

  if (blockIdx.x < 128) {
    // Base: 8 tb rows (4 h_pair rows) x all 512 n
    const int tbc = blockIdx.x;
    const float* src = hp + tbc * 4 * 1024;
#pragma unroll
    for (int i = 0; i < 2; ++i)
      load_lds16(src + (wave * 2 + i) * 256 + lane * 4,
                 hl + (wave * 2 + i) * 256);
    __syncthreads();
    const int n = tid;
    v2f acc[4] = {v2(0.f), v2(0.f), v2(0.f), v2(0.f)};
    const float* wrow = w_add + n * N_;
    for (int m = 0; m < N_; m += 4) {
      const float4 w4 = *(const float4*)&wrow[m];
#pragma unroll
      for (int p = 0; p < 4; ++p) {
        const float4 ha = *(const float4*)&hl[p * 1024 + m * 2];
        const float4 hb = *(const float4*)&hl[p * 1024 + m * 2 + 4];
        acc[p] = __builtin_elementwise_fma(v2(w4.x), mk2(ha.x, ha.y), acc[p]);
        acc[p] = __builtin_elementwise_fma(v2(w4.y), mk2(ha.z, ha.w), acc[p]);
        acc[p] = __builtin_elementwise_fma(v2(w4.z), mk2(hb.x, hb.y), acc[p]);
        acc[p] = __builtin_elementwise_fma(v2(w4.w), mk2(hb.z, hb.w), acc[p]);
      }
    }
    const float bad = b_add[n];
#pragma unroll
    for (int p = 0; p < 4; ++p) {
      const int tbp = tbc * 4 + p;
      const int tbe = tbp + 8 * (tbp >> 3);  // t even row; odd = +8
      z0[tbe * N_ + n] = acc[p].x + bad;
      z0[(tbe + 8) * N_ + n] = acc[p].y + bad;
    }
  } else {
    // Gram: block (b, t-chunk of 16); W[t][s] = eta*lam^(t-1-s)*G(s,t), 0 if s>=t
    const int gb = blockIdx.x - 128;
    const int b = gb >> 3, tc = gb & 7;
    {
      const int q = wave;  // 8 rows (t2 = tc*8+q)
      const float* rsrc = hp + ((tc * 8 + q) * 8 + b) * 1024;
#pragma unroll
      for (int sgm = 0; sgm < 4; ++sgm)
        load_lds16(rsrc + sgm * 256 + lane * 4, hl + q * 1024 + sgm * 256);
    }
    __syncthreads();
    const int s = tid & 127, tq = tid >> 7;
    const int tmax = tc * 16 + tq * 4 + 3;
    v2f acc[2] = {v2(0.f), v2(0.f)};
    if (s < tmax) {
      const float* srow = hp + ((s >> 1) * 8 + b) * 1024 + (s & 1);
#pragma unroll 4
      for (int n = 0; n < N_; ++n) {
        const float hs = srow[n * 2];
        const float2 hA = *(const float2*)&hl[(tq * 2 + 0) * 1024 + n * 2];
        const float2 hB = *(const float2*)&hl[(tq * 2 + 1) * 1024 + n * 2];
        acc[0] = __builtin_elementwise_fma(v2(hs), mk2(hA.x, hA.y), acc[0]);
        acc[1] = __builtin_elementwise_fma(v2(hs), mk2(hB.x, hB.y), acc[1]);
      }
    }
    const float l2lam = __log2f(lam);
#pragma unroll
    for (int i = 0; i < 4; ++i) {
      const int t = tc * 16 + tq * 4 + i;
      const float gv = (i & 1) ? acc[i >> 1].y : acc[i >> 1].x;
      float w = 0.f;
      if (s < t) w = eta * exp2f((float)(t - 1 - s) * l2lam) * gv;
      Wsc[(b * T_ + t) * T_ + s] = w;
    }
  }
}

// ---- scan: 64 blocks (b x n-chunk 64). 8 waves x 2 t-rows per 16-tile.
// history = parallel FMAs vs u_lds; triangle = column-form on wave 0. ----
__global__ void __launch_bounds__(NTHREADS, 1)
np_scan(float* __restrict__ ws) {
  __shared__ float ul[T_][64];    // 32 KB u history
  __shared__ float zx[16][64];    // 4 KB z exchange
  __shared__ float Wtile[16][16]; // 1 KB in-tile W
  const int b = blockIdx.x >> 3, nc = blockIdx.x & 7;
  const int wave = threadIdx.x >> 6, lane = threadIdx.x & 63;
  float* z0 = ws + Z0_OFF;
  const float* Wb = ws + WS_OFF + b * T_ * T_;

  const int ta = 2 * wave, tb2 = 2 * wave + 1;
  const int ncol = nc * 64 + lane;

  float za = z0[(ta * B_ + b) * N_ + ncol];
  float zb = z0[(tb2 * B_ + b) * N_ + ncol];

  for (int j = 0; j < 8; ++j) {
    const int t0 = j * 16;
    const float* wga = Wb + (t0 + ta) * T_;
    const float* wgb = Wb + (t0 + tb2) * T_;
    float zna = 0.f, znb = 0.f;
    if (j < 7) {
      zna = z0[((t0 + 16 + ta) * B_ + b) * N_ + ncol];
      znb = z0[((t0 + 16 + tb2) * B_ + b) * N_ + ncol];
    }
    // stage this tile's 16x16 W block (each wave: its 2 rows)
    if (lane < 4) {
      *(float4*)&Wtile[ta][lane * 4] = *(const float4*)&wga[t0 + lane * 4];
      *(float4*)&Wtile[tb2][lane * 4] = *(const float4*)&wgb[t0 + lane * 4];
    }
    // history over s < t0
    float ha0 = 0.f, ha1 = 0.f, hb0 = 0.f, hb1 = 0.f;
#pragma unroll 2
    for (int s4 = 0; s4 < t0; s4 += 4) {
      const float4 wa = *(const float4*)&wga[s4];
      const float4 wb = *(const float4*)&wgb[s4];
      const float u0 = ul[s4 + 0][lane], u1 = ul[s4 + 1][lane];
      const float u2 = ul[s4 + 2][lane], u3 = ul[s4 + 3][lane];
      ha0 = __builtin_fmaf(wa.x, u0, ha0);
      ha1 = __builtin_fmaf(wa.y, u1, ha1);
      ha0 = __builtin_fmaf(wa.z, u2, ha0);
      ha1 = __builtin_fmaf(wa.w, u3, ha1);
      hb0 = __builtin_fmaf(wb.x, u0, hb0);
      hb1 = __builtin_fmaf(wb.y, u1, hb1);
      hb0 = __builtin_fmaf(wb.z, u2, hb0);
      hb1 = __builtin_fmaf(wb.w, u3, hb1);
    }
    zx[ta][lane] = za + (ha0 + ha1);
    zx[tb2][lane] = zb + (hb0 + hb1);
    __syncthreads();
    if (wave == 0) {
      float z[16], uv[16];
#pragma unroll
      for (int i = 0; i < 16; ++i) z[i] = zx[i][lane];
#pragma unroll
      for (int i = 0; i < 16; ++i) {
        const float u = sigmoid_f(z[i]);
        uv[i] = u;
        z0[((t0 + i) * B_ + b) * N_ + ncol] = u;  // in-place u output
#pragma unroll
        for (int tt = i + 1; tt < 16; ++tt)
          z[tt] = __builtin_fmaf(u, Wtile[tt][i], z[tt]);
      }
#pragma unroll
      for (int i = 0; i < 16; ++i) ul[t0 + i][lane] = uv[i];
    }
    __syncthreads();
    za = zna;
    zb = znb;
  }
}

// ---- final: y(t,b) = sigmoid(w_final . u(t,b) + b_final) ----
__global__ void __launch_bounds__(NTHREADS)
np_final(const float* __restrict__ ws, const float* __restrict__ w_final,
         const float* __restrict__ b_final, float* __restrict__ out) {
  const int wave = threadIdx.x >> 6, lane = threadIdx.x & 63;
  const int tb = blockIdx.x * 8 + wave;
  const float* u = ws + Z0_OFF + tb * N_ + lane * 8;
  const float4 a = *(const float4*)u, c = *(const float4*)(u + 4);
  const float4 wa = *(const float4*)&w_final[lane * 8];
  const float4 wc = *(const float4*)&w_final[lane * 8 + 4];
  float d = a.x * wa.x + a.y * wa.y + a.z * wa.z + a.w * wa.w +
            c.x * wc.x + c.y * wc.y + c.z * wc.z + c.w * wc.w;
  d = dpp_wave_sum(d);
  if (lane == 0) out[tb] = sigmoid_f(d + b_final[0]);
}

// ================= fallback path (R5) =================

__global__ void __launch_bounds__(NTHREADS, 2)
fb_part1(const float* __restrict__ x, const float* __restrict__ w_mult,
         const float* __restrict__ b_mult, const float* __restrict__ p_lm,
         const float* __restrict__ p_em, float* __restrict__ ws) {
  const int g = blockIdx.x & 7, sub = blockIdx.x >> 3;
  const int wave = threadIdx.x >> 6, lane = threadIdx.x & 63;
  const int n0 = (sub * 8 + wave) * 2;
  __shared__ float xs[2][CH][D_];
  const float lam = sigmoid_f(p_lm[0]);
  const float eta = p_em[0];
  const v2f lam2 = v2(lam), klam2 = v2(1.f - lam);
  v2f wm[2][2], Bm[2][2];
  float bm[2];
#pragma unroll
  for (int r = 0; r < 2; ++r) {
    bm[r] = b_mult[n0 + r];
#pragma unroll
    for (int c = 0; c < 2; ++c) {
      wm[r][c] = *(const v2f*)&w_mult[(n0 + r) * D_ + c * 128 + 2 * lane];
      Bm[r][c] = v2(1.f);
    }
  }
  auto issue_stage = [&](int c) {
#pragma unroll
    for (int k = 0; k < 2; ++k) {
      const int row = k * 8 + wave;
      load_lds16(&x[((c * CH + row) * B_ + g) * D_ + 4 * lane],
                 &xs[c & 1][row][0]);
    }
  };
  issue_stage(0);
  __syncthreads();
  v2f xv[2][2];
  auto ldx = [&](int buf, int cb, int tl) {
    xv[buf][0] = *(const v2f*)&xs[cb][tl][2 * lane];
    xv[buf][1] = *(const v2f*)&xs[cb][tl][128 + 2 * lane];
  };
  for (int c = 0; c < NC; ++c) {
    if (c + 1 < NC) issue_stage(c + 1);
    const int cb = c & 1;
    ldx(0, cb, 0);
#pragma unroll
    for (int tl = 0; tl < CH; ++tl) {
      const int buf = tl & 1;
      if (tl + 1 < CH) ldx(buf ^ 1, cb, tl + 1);
      float hmv[2];
#pragma unroll
      for (int r = 0; r < 2; ++r) {
        v2f a = wm[r][0] * xv[buf][0] * Bm[r][0];
        a = __builtin_elementwise_fma(wm[r][1] * xv[buf][1], Bm[r][1], a);
        const float z = dpp_wave_sum(a.x + a.y) + bm[r];
        const float hm = tanh_f(z);
        hmv[r] = hm;
        const v2f c2 = v2(eta * hm);
#pragma unroll
        for (int cc = 0; cc < 2; ++cc) {
          v2f inner = __builtin_elementwise_fma(c2, xv[buf][cc], klam2);
          Bm[r][cc] = __builtin_elementwise_fma(lam2, Bm[r][cc], inner);
        }
      }
      if (lane == 0) {
        v2f hv2;
        hv2.x = hmv[0];
        hv2.y = hmv[1];
        *(v2f*)(ws + ((c * CH + tl) * B_ + g) * N_ + n0) = hv2;
      }
    }
    __syncthreads();
  }
}

__global__ void __launch_bounds__(NTHREADS, 2)
fb_part2(const float* __restrict__ w_add, const float* __restrict__ b_add,
         const float* __restrict__ w_final, const float* __restrict__ p_la,
         const float* __restrict__ p_ea, float* __restrict__ ws) {
  const int g = blockIdx.x & 7, sub = blockIdx.x >> 3;
  const int wave = threadIdx.x >> 6, lane = threadIdx.x & 63;
  const int n0 = (sub * 8 + wave) * 2;
  __shared__ float hs[2][CH][N_];
  const float lam = sigmoid_f(p_la[0]);
  const float eta = p_ea[0];
  const v2f lam2 = v2(lam);
  const float klam = 1.f - lam;
  v2f Sa[2][4], wb[2][4];
  float ba[2], wf[2];
#pragma unroll
  for (int r = 0; r < 2; ++r) {
    ba[r] = b_add[n0 + r];
    wf[r] = w_final[n0 + r];
#pragma unroll
    for (int c = 0; c < 4; ++c) {
      const v2f wa = *(const v2f*)&w_add[(n0 + r) * N_ + c * 128 + 2 * lane];
      Sa[r][c] = wa;
      wb[r][c] = wa * klam;
    }
  }
  const float* hsrc = ws;
  float* part = ws + HOFF;
  auto issue_stage = [&](int c) {
#pragma unroll
    for (int k = 0; k < 2; ++k) {
      const int row = k * 8 + wave;
#pragma unroll
      for (int jj = 0; jj < 2; ++jj)
        load_lds16(&hsrc[((c * CH + row) * B_ + g) * N_ + jj * 256 + 4 * lane],
                   &hs[c & 1][row][jj * 256]);
    }
  };
  issue_stage(0);
  __syncthreads();
  v2f hv[2][4];
  auto ldh = [&](int buf, int cb, int tl) {
#pragma unroll
    for (int cc = 0; cc < 4; ++cc)
      hv[buf][cc] = *(const v2f*)&hs[cb][tl][cc * 128 + 2 * lane];
  };
  for (int c = 0; c < NC; ++c) {
    if (c + 1 < NC) issue_stage(c + 1);
    const int cb = c & 1;
    ldh(0, cb, 0);
#pragma unroll
    for (int tl = 0; tl < CH; ++tl) {
      const int buf = tl & 1;
      if (tl + 1 < CH) ldh(buf ^ 1, cb, tl + 1);
      float py = 0.f;
#pragma unroll
      for (int r = 0; r < 2; ++r) {
        v2f a0 = Sa[r][0] * hv[buf][0];
        v2f a1 = Sa[r][1] * hv[buf][1];
        a0 = __builtin_elementwise_fma(Sa[r][2], hv[buf][2], a0);
        a1 = __builtin_elementwise_fma(Sa[r][3], hv[buf][3], a1);
        const v2f a = a0 + a1;
        const float z = dpp_wave_sum(a.x + a.y) + ba[r];
        const float ha = sigmoid_f(z);
        const v2f c2 = v2(eta * ha);
#pragma unroll
        for (int cc = 0; cc < 4; ++cc) {
          v2f inner = __builtin_elementwise_fma(c2, hv[buf][cc], wb[r][cc]);
          Sa[r][cc] = __builtin_elementwise_fma(lam2, Sa[r][cc], inner);
        }
        py = __builtin_fmaf(wf[r], ha, py);
      }
      if (lane == 0)
        part[((c * CH + tl) * B_ + g) * 256 + sub * 8 + wave] = py;
    }
    __syncthreads();
  }
}

__global__ void __launch_bounds__(NTHREADS)
fb_final(const float* __restrict__ ws, const float* __restrict__ b_final,
         float* __restrict__ out) {
  const int wave = threadIdx.x >> 6, lane = threadIdx.x & 63;
  const int tb = blockIdx.x * 8 + wave;
  const float4 v = *(const float4*)(ws + HOFF + tb * 256 + lane * 4);
  const float s = dpp_wave_sum((v.x + v.y) + (v.z + v.w));
  if (lane == 0) out[tb] = sigmoid_f(s + b_final[0]);
}

// ================= launch =================

extern "C" void kernel_launch(void* const* d_in, const int* in_sizes, int n_in,
                              void* d_out, int out_size, void* d_ws,
                              size_t ws_size, hipStream_t stream) {
  const float* x       = (const float*)d_in[0];
  const float* w_mult  = (const float*)d_in[1];
  const float* b_mult  = (const float*)d_in[2];
  const float* w_add   = (const float*)d_in[3];
  const float* b_add   = (const float*)d_in[4];
  const float* w_final = (const float*)d_in[5];
  const float* b_final = (const float*)d_in[6];
  const float* p_lm    = (const float*)d_in[7];
  const float* p_la    = (const float*)d_in[8];
  const float* p_em    = (const float*)d_in[9];
  const float* p_ea    = (const float*)d_in[10];
  float* out = (float*)d_out;
  float* ws  = (float*)d_ws;

  if (ws_size >= WS_NEED) {
    hipLaunchKernelGGL(np_part1, dim3(256), dim3(NTHREADS), 0, stream,
                       x, w_mult, b_mult, p_lm, p_em, ws);
    hipLaunchKernelGGL(np_mid, dim3(192), dim3(NTHREADS), 0, stream,
                       w_add, b_add, p_la, p_ea, ws);
    hipLaunchKernelGGL(np_scan, dim3(64), dim3(NTHREADS), 0, stream, ws);
    hipLaunchKernelGGL(np_final, dim3(128), dim3(NTHREADS), 0, stream,
                       ws, w_final, b_final, out);
  } else {
    hipLaunchKernelGGL(fb_part1, dim3(256), dim3(NTHREADS), 0, stream,
                       x, w_mult, b_mult, p_lm, p_em, ws);
    hipLaunchKernelGGL(fb_part2, dim3(256), dim3(NTHREADS), 0, stream,
                       w_add, b_add, w_final, p_la, p_ea, ws);
    hipLaunchKernelGGL(fb_final, dim3(128), dim3(NTHREADS), 0, stream,
                       ws, b_final, out);
  }
}

// Round 7
// 98.307 us; speedup vs baseline: 1.7845x; 1.7845x over previous
//
#include <hip/hip_runtime.h>
#include <cstdint>

// HebbFF T=128,B=8,N=512,D=256,O=1.
// R7: Gram-matrix path, rebuilt around split-K (lane l owns k in {l+64j}):
//   np_part1: h_mult chain; all x staged to LDS once (128KB, no barriers in
//             chain), 4-slot static prefetch ring; emits h_pair[t2*8+b][n][2].
//   np_mid:   blocks 0..511 base GEMM z0 = h@w_add^T + b_add (w_add reads
//             coalesced b32 per lane-slice, h fragments in regs, DPP reduce);
//             blocks 512..639 Gram -> W[b][t][s] with lambda epilogue.
//   np_scan:  W_b staged fully in LDS; 16-step tiles: parallel history FMAs,
//             column-form triangle on wave0.
//   np_final: y = sigmoid(w_final.u + b_final).
// ws (floats): hp@0 (524288) | z0/u@524288 (524288) | W@1048576 (131072)
//   = 4.5 MB. Fallback to R5 path if ws smaller.

#define T_ 128
#define B_ 8
#define N_ 512
#define D_ 256
#define HP_OFF 0
#define Z0_OFF 524288
#define WS_OFF 1048576
#define WS_NEED ((size_t)(1048576 + 131072) * 4)
#define HOFF (T_ * B_ * N_)   // fallback layout
#define CH 16
#define NC (T_ / CH)

typedef float v2f __attribute__((ext_vector_type(2)));

__device__ __forceinline__ v2f v2(float s) { v2f r; r.x = s; r.y = s; return r; }

__device__ __forceinline__ void load_lds16(const float* g, float* l) {
  __builtin_amdgcn_global_load_lds(
      (const __attribute__((address_space(1))) uint32_t*)(const void*)g,
      (__attribute__((address_space(3))) uint32_t*)(void*)l, 16, 0, 0);
}

#define DPP1(v, ctrl)                                                          \
  v += __int_as_float(                                                         \
      __builtin_amdgcn_update_dpp(0, __float_as_int(v), ctrl, 0xf, 0xf, true))

// sum across 64 lanes; total lands in lane 63 (no broadcast)
__device__ __forceinline__ float dpp_red(float v) {
  DPP1(v, 0x111); DPP1(v, 0x112); DPP1(v, 0x114); DPP1(v, 0x118);
  DPP1(v, 0x142); DPP1(v, 0x143);
  return v;
}
__device__ __forceinline__ v2f dpp_red2(v2f v) {
  float a = v.x, b = v.y;
  DPP1(a, 0x111); DPP1(b, 0x111); DPP1(a, 0x112); DPP1(b, 0x112);
  DPP1(a, 0x114); DPP1(b, 0x114); DPP1(a, 0x118); DPP1(b, 0x118);
  DPP1(a, 0x142); DPP1(b, 0x142); DPP1(a, 0x143); DPP1(b, 0x143);
  v.x = a; v.y = b;
  return v;
}
// broadcast variant
__device__ __forceinline__ float dpp_wave_sum(float v) {
  v = dpp_red(v);
  return __int_as_float(__builtin_amdgcn_readlane(__float_as_int(v), 63));
}
__device__ __forceinline__ float sigmoid_f(float z) {
  return __builtin_amdgcn_rcpf(1.f + __expf(-z));
}
__device__ __forceinline__ float tanh_f(float z) {
  return 1.f - 2.f * __builtin_amdgcn_rcpf(1.f + __expf(2.f * z));
}

// ---------------- np_part1: h_mult / A_mult chain ----------------
__global__ void __launch_bounds__(512, 1)
np_part1(const float* __restrict__ x, const float* __restrict__ w_mult,
         const float* __restrict__ b_mult, const float* __restrict__ p_lm,
         const float* __restrict__ p_em, float* __restrict__ ws) {
  const int g = blockIdx.x & 7, sub = blockIdx.x >> 3;
  const int wave = threadIdx.x >> 6, lane = threadIdx.x & 63;
  const int n0 = (sub * 8 + wave) * 2;

  __shared__ float xs[T_][D_];  // 128 KB: ALL x rows for batch g

#pragma unroll
  for (int i = 0; i < 16; ++i) {
    const int r = wave * 16 + i;
    load_lds16(&x[(r * B_ + g) * D_ + 4 * lane], &xs[r][0]);
  }

  const float lam = sigmoid_f(p_lm[0]);
  const float eta = p_em[0];
  const v2f lam2 = v2(lam), klam2 = v2(1.f - lam);

  v2f wm[2][2], Bm[2][2];
  float bm[2];
#pragma unroll
  for (int r = 0; r < 2; ++r) {
    bm[r] = b_mult[n0 + r];
#pragma unroll
    for (int c = 0; c < 2; ++c) {
      wm[r][c] = *(const v2f*)&w_mult[(n0 + r) * D_ + c * 128 + 2 * lane];
      Bm[r][c] = v2(1.f);
    }
  }
  __syncthreads();  // x staged

  float* hp = ws + HP_OFF;
  v2f xv[4][2];
#define LDX(slot, t)                                                           \
  {                                                                            \
    xv[slot][0] = *(const v2f*)&xs[t][2 * lane];                               \
    xv[slot][1] = *(const v2f*)&xs[t][128 + 2 * lane];                         \
  }
  LDX(0, 0) LDX(1, 1) LDX(2, 2)

  float ph0 = 0.f, ph1 = 0.f;
  for (int t4 = 0; t4 < T_; t4 += 4) {
#pragma unroll
    for (int j = 0; j < 4; ++j) {
      const int t = t4 + j;
      if (t + 3 < T_) LDX((j + 3) & 3, t + 3)
      float hmv[2];
#pragma unroll
      for (int r = 0; r < 2; ++r) {
        v2f a = wm[r][0] * xv[j][0] * Bm[r][0];
        a = __builtin_elementwise_fma(wm[r][1] * xv[j][1], Bm[r][1], a);
        const float z = dpp_wave_sum(a.x + a.y) + bm[r];
        const float hm = tanh_f(z);
        hmv[r] = hm;
        const v2f c2 = v2(eta * hm);
#pragma unroll
        for (int cc = 0; cc < 2; ++cc) {
          v2f inner = __builtin_elementwise_fma(c2, xv[j][cc], klam2);
          Bm[r][cc] = __builtin_elementwise_fma(lam2, Bm[r][cc], inner);
        }
      }
      if (j & 1) {
        if (lane == 0) {
          const int t2 = t >> 1;
          *(float4*)(hp + ((t2 * B_ + g) * N_ + n0) * 2) =
              make_float4(ph0, hmv[0], ph1, hmv[1]);
        }
      } else {
        ph0 = hmv[0];
        ph1 = hmv[1];
      }
    }
  }
#undef LDX
}

// ---------------- np_mid: base GEMM + Gram (split-K) ----------------
// 640 blocks x 256 thr. Blocks [0,512): base; [512,640): gram.
__global__ void __launch_bounds__(256)
np_mid(const float* __restrict__ w_add, const float* __restrict__ b_add,
       const float* __restrict__ p_la, const float* __restrict__ p_ea,
       float* __restrict__ ws) {
  __shared__ float hl[4 * 1024];  // 16 KB (gram uses 4 rows; base 2)
  const int wave = threadIdx.x >> 6, lane = threadIdx.x & 63;
  const float* hp = ws + HP_OFF;
  float* z0 = ws + Z0_OFF;
  float* Wsc = ws + WS_OFF;
  const float lam = sigmoid_f(p_la[0]);
  const float eta = p_ea[0];

  if (blockIdx.x < 512) {
    // ---- base: 2 h_pair rows (prA, prA+1) x 256 cols (half nh) ----
    const int prA = (blockIdx.x >> 1) * 2;
    const int nh = blockIdx.x & 1;
    // stage 2 hp rows (8 KB): wave w -> row w>>1, half w&1, 2 calls
#pragma unroll
    for (int i = 0; i < 2; ++i)
      load_lds16(&hp[(prA + (wave >> 1)) * 1024 + (wave & 1) * 512 + i * 256 +
                     4 * lane],
                 &hl[(wave >> 1) * 1024 + (wave & 1) * 512 + i * 256]);
    __syncthreads();
    v2f hv[2][8];
#pragma unroll
    for (int p = 0; p < 2; ++p)
#pragma unroll
      for (int j = 0; j < 8; ++j)
        hv[p][j] = ((const v2f*)hl)[p * 512 + lane + 64 * j];

    const int nbase = nh * 256 + wave * 64;
    for (int nn = 0; nn < 64; ++nn) {
      const int n = nbase + nn;
      const float* wrow = w_add + n * N_;
      float wv[8];
#pragma unroll
      for (int j = 0; j < 8; ++j) wv[j] = wrow[lane + 64 * j];
      const float bias = b_add[n];
#pragma unroll
      for (int p = 0; p < 2; ++p) {
        v2f a = hv[p][0] * v2(wv[0]);
#pragma unroll
        for (int j = 1; j < 8; ++j)
          a = __builtin_elementwise_fma(hv[p][j], v2(wv[j]), a);
        a = dpp_red2(a);
        if (lane == 63) {
          const int pr = prA + p;
          const int rowe = 16 * (pr >> 3) + (pr & 7);  // t even
          z0[rowe * N_ + n] = a.x + bias;
          z0[(rowe + 8) * N_ + n] = a.y + bias;
        }
      }
    }
  } else {
    // ---- gram: block (b, q): t rows [q*8, q*8+8) vs all s < t ----
    const int bi2 = blockIdx.x - 512;
    const int b = bi2 & 7, q = bi2 >> 3;  // q in [0,16)
    // stage 4 hp rows (q*4+i)*8+b (16 KB): wave w -> row w, 4 calls
#pragma unroll
    for (int i = 0; i < 4; ++i)
      load_lds16(&hp[((q * 4 + wave) * 8 + b) * 1024 + i * 256 + 4 * lane],
                 &hl[wave * 1024 + i * 256]);
    __syncthreads();
    v2f hv[4][8];
#pragma unroll
    for (int i = 0; i < 4; ++i)
#pragma unroll
      for (int j = 0; j < 8; ++j)
        hv[i][j] = ((const v2f*)hl)[i * 512 + lane + 64 * j];

    const float l2lam = __log2f(lam);
    const int tlim = q * 8 + 7;  // s can be at most q*8+6
    for (int tp = wave; tp < tlim; tp += 4) {
      const float* hrow = hp + ((tp >> 1) * 8 + b) * 1024 + (tp & 1);
      float wv[8];
#pragma unroll
      for (int j = 0; j < 8; ++j) wv[j] = hrow[2 * (lane + 64 * j)];
#pragma unroll
      for (int i = 0; i < 4; ++i) {
        v2f a = hv[i][0] * v2(wv[0]);
#pragma unroll
        for (int j = 1; j < 8; ++j)
          a = __builtin_elementwise_fma(hv[i][j], v2(wv[j]), a);
        a = dpp_red2(a);
        if (lane == 63) {
          const int te = q * 8 + 2 * i;
          if (tp < te)
            Wsc[(b * T_ + te) * T_ + tp] =
                eta * exp2f(l2lam * (float)(te - 1 - tp)) * a.x;
          if (tp < te + 1)
            Wsc[(b * T_ + te + 1) * T_ + tp] =
                eta * exp2f(l2lam * (float)(te - tp)) * a.y;
        }
      }
    }
  }
}

// ---------------- np_scan: sequential sigmoid scan ----------------
__global__ void __launch_bounds__(512, 1)
np_scan(float* __restrict__ ws) {
  __shared__ float Wl[T_][T_];   // 64 KB
  __shared__ float ul[T_][64];   // 32 KB
  __shared__ float zx[16][64];   // 4 KB
  const int b = blockIdx.x >> 3, nc = blockIdx.x & 7;
  const int wave = threadIdx.x >> 6, lane = threadIdx.x & 63;
  float* z0 = ws + Z0_OFF;
  const float* Wb = ws + WS_OFF + b * T_ * T_;

  // stage full W_b: wave w -> rows [w*16, w*16+16), 2 rows per call
#pragma unroll
  for (int i = 0; i < 8; ++i) {
    const int r2 = wave * 16 + i * 2;
    load_lds16(&Wb[r2 * T_ + 4 * lane], &Wl[r2][0]);
  }

  const int ta = 2 * wave, tb2 = 2 * wave + 1;
  const int ncol = nc * 64 + lane;

  float za = z0[(ta * B_ + b) * N_ + ncol];
  float zb = z0[(tb2 * B_ + b) * N_ + ncol];
  __syncthreads();  // W staged

  for (int j = 0; j < 8; ++j) {
    const int t0 = j * 16;
    float zna = 0.f, znb = 0.f;
    if (j < 7) {
      zna = z0[((t0 + 16 + ta) * B_ + b) * N_ + ncol];
      znb = z0[((t0 + 16 + tb2) * B_ + b) * N_ + ncol];
    }
    // history over s < t0 (u in ul, W in LDS)
    float ha0 = 0.f, ha1 = 0.f, hb0 = 0.f, hb1 = 0.f;
#pragma unroll 2
    for (int s4 = 0; s4 < t0; s4 += 4) {
      const float4 wa = *(const float4*)&Wl[t0 + ta][s4];
      const float4 wb = *(const float4*)&Wl[t0 + tb2][s4];
      const float u0 = ul[s4 + 0][lane], u1 = ul[s4 + 1][lane];
      const float u2 = ul[s4 + 2][lane], u3 = ul[s4 + 3][lane];
      ha0 = __builtin_fmaf(wa.x, u0, ha0);
      ha1 = __builtin_fmaf(wa.y, u1, ha1);
      ha0 = __builtin_fmaf(wa.z, u2, ha0);
      ha1 = __builtin_fmaf(wa.w, u3, ha1);
      hb0 = __builtin_fmaf(wb.x, u0, hb0);
      hb1 = __builtin_fmaf(wb.y, u1, hb1);
      hb0 = __builtin_fmaf(wb.z, u2, hb0);
      hb1 = __builtin_fmaf(wb.w, u3, hb1);
    }
    zx[ta][lane] = za + (ha0 + ha1);
    zx[tb2][lane] = zb + (hb0 + hb1);
    __syncthreads();
    if (wave == 0) {
      float z[16], uv[16];
#pragma unroll
      for (int i = 0; i < 16; ++i) z[i] = zx[i][lane];
#pragma unroll
      for (int i = 0; i < 16; ++i) {
        const float u = sigmoid_f(z[i]);
        uv[i] = u;
        z0[((t0 + i) * B_ + b) * N_ + ncol] = u;  // in-place u
#pragma unroll
        for (int tt = i + 1; tt < 16; ++tt)
          z[tt] = __builtin_fmaf(u, Wl[t0 + tt][t0 + i], z[tt]);
      }
#pragma unroll
      for (int i = 0; i < 16; ++i) ul[t0 + i][lane] = uv[i];
    }
    __syncthreads();
    za = zna;
    zb = znb;
  }
}

// ---------------- np_final ----------------
__global__ void __launch_bounds__(512)
np_final(const float* __restrict__ ws, const float* __restrict__ w_final,
         const float* __restrict__ b_final, float* __restrict__ out) {
  const int wave = threadIdx.x >> 6, lane = threadIdx.x & 63;
  const int tb = blockIdx.x * 8 + wave;
  const float* u = ws + Z0_OFF + tb * N_ + lane * 8;
  const float4 a = *(const float4*)u, c = *(const float4*)(u + 4);
  const float4 wa = *(const float4*)&w_final[lane * 8];
  const float4 wc = *(const float4*)&w_final[lane * 8 + 4];
  float d = a.x * wa.x + a.y * wa.y + a.z * wa.z + a.w * wa.w +
            c.x * wc.x + c.y * wc.y + c.z * wc.z + c.w * wc.w;
  d = dpp_wave_sum(d);
  if (lane == 0) out[tb] = sigmoid_f(d + b_final[0]);
}

// ================= fallback path (R5) =================

__global__ void __launch_bounds__(512, 2)
fb_part1(const float* __restrict__ x, const float* __restrict__ w_mult,
         const float* __restrict__ b_mult, const float* __restrict__ p_lm,
         const float* __restrict__ p_em, float* __restrict__ ws) {
  const int g = blockIdx.x & 7, sub = blockIdx.x >> 3;
  const int wave = threadIdx.x >> 6, lane = threadIdx.x & 63;
  const int n0 = (sub * 8 + wave) * 2;
  __shared__ float xs[2][CH][D_];
  const float lam = sigmoid_f(p_lm[0]);
  const float eta = p_em[0];
  const v2f lam2 = v2(lam), klam2 = v2(1.f - lam);
  v2f wm[2][2], Bm[2][2];
  float bm[2];
#pragma unroll
  for (int r = 0; r < 2; ++r) {
    bm[r] = b_mult[n0 + r];
#pragma unroll
    for (int c = 0; c < 2; ++c) {
      wm[r][c] = *(const v2f*)&w_mult[(n0 + r) * D_ + c * 128 + 2 * lane];
      Bm[r][c] = v2(1.f);
    }
  }
  auto issue_stage = [&](int c) {
#pragma unroll
    for (int k = 0; k < 2; ++k) {
      const int row = k * 8 + wave;
      load_lds16(&x[((c * CH + row) * B_ + g) * D_ + 4 * lane],
                 &xs[c & 1][row][0]);
    }
  };
  issue_stage(0);
  __syncthreads();
  v2f xv[2][2];
  auto ldx = [&](int buf, int cb, int tl) {
    xv[buf][0] = *(const v2f*)&xs[cb][tl][2 * lane];
    xv[buf][1] = *(const v2f*)&xs[cb][tl][128 + 2 * lane];
  };
  for (int c = 0; c < NC; ++c) {
    if (c + 1 < NC) issue_stage(c + 1);
    const int cb = c & 1;
    ldx(0, cb, 0);
#pragma unroll
    for (int tl = 0; tl < CH; ++tl) {
      const int buf = tl & 1;
      if (tl + 1 < CH) ldx(buf ^ 1, cb, tl + 1);
      float hmv[2];
#pragma unroll
      for (int r = 0; r < 2; ++r) {
        v2f a = wm[r][0] * xv[buf][0] * Bm[r][0];
        a = __builtin_elementwise_fma(wm[r][1] * xv[buf][1], Bm[r][1], a);
        const float z = dpp_wave_sum(a.x + a.y) + bm[r];
        const float hm = tanh_f(z);
        hmv[r] = hm;
        const v2f c2 = v2(eta * hm);
#pragma unroll
        for (int cc = 0; cc < 2; ++cc) {
          v2f inner = __builtin_elementwise_fma(c2, xv[buf][cc], klam2);
          Bm[r][cc] = __builtin_elementwise_fma(lam2, Bm[r][cc], inner);
        }
      }
      if (lane == 0) {
        v2f hv2;
        hv2.x = hmv[0];
        hv2.y = hmv[1];
        *(v2f*)(ws + ((c * CH + tl) * B_ + g) * N_ + n0) = hv2;
      }
    }
    __syncthreads();
  }
}

__global__ void __launch_bounds__(512, 2)
fb_part2(const float* __restrict__ w_add, const float* __restrict__ b_add,
         const float* __restrict__ w_final, const float* __restrict__ p_la,
         const float* __restrict__ p_ea, float* __restrict__ ws) {
  const int g = blockIdx.x & 7, sub = blockIdx.x >> 3;
  const int wave = threadIdx.x >> 6, lane = threadIdx.x & 63;
  const int n0 = (sub * 8 + wave) * 2;
  __shared__ float hs[2][CH][N_];
  const float lam = sigmoid_f(p_la[0]);
  const float eta = p_ea[0];
  const v2f lam2 = v2(lam);
  const float klam = 1.f - lam;
  v2f Sa[2][4], wb[2][4];
  float ba[2], wf[2];
#pragma unroll
  for (int r = 0; r < 2; ++r) {
    ba[r] = b_add[n0 + r];
    wf[r] = w_final[n0 + r];
#pragma unroll
    for (int c = 0; c < 4; ++c) {
      const v2f wa = *(const v2f*)&w_add[(n0 + r) * N_ + c * 128 + 2 * lane];
      Sa[r][c] = wa;
      wb[r][c] = wa * klam;
    }
  }
  const float* hsrc = ws;
  float* part = ws + HOFF;
  auto issue_stage = [&](int c) {
#pragma unroll
    for (int k = 0; k < 2; ++k) {
      const int row = k * 8 + wave;
#pragma unroll
      for (int jj = 0; jj < 2; ++jj)
        load_lds16(&hsrc[((c * CH + row) * B_ + g) * N_ + jj * 256 + 4 * lane],
                   &hs[c & 1][row][jj * 256]);
    }
  };
  issue_stage(0);
  __syncthreads();
  v2f hv[2][4];
  auto ldh = [&](int buf, int cb, int tl) {
#pragma unroll
    for (int cc = 0; cc < 4; ++cc)
      hv[buf][cc] = *(const v2f*)&hs[cb][tl][cc * 128 + 2 * lane];
  };
  for (int c = 0; c < NC; ++c) {
    if (c + 1 < NC) issue_stage(c + 1);
    const int cb = c & 1;
    ldh(0, cb, 0);
#pragma unroll
    for (int tl = 0; tl < CH; ++tl) {
      const int buf = tl & 1;
      if (tl + 1 < CH) ldh(buf ^ 1, cb, tl + 1);
      float py = 0.f;
#pragma unroll
      for (int r = 0; r < 2; ++r) {
        v2f a0 = Sa[r][0] * hv[buf][0];
        v2f a1 = Sa[r][1] * hv[buf][1];
        a0 = __builtin_elementwise_fma(Sa[r][2], hv[buf][2], a0);
        a1 = __builtin_elementwise_fma(Sa[r][3], hv[buf][3], a1);
        const v2f a = a0 + a1;
        const float z = dpp_wave_sum(a.x + a.y) + ba[r];
        const float ha = sigmoid_f(z);
        const v2f c2 = v2(eta * ha);
#pragma unroll
        for (int cc = 0; cc < 4; ++cc) {
          v2f inner = __builtin_elementwise_fma(c2, hv[buf][cc], wb[r][cc]);
          Sa[r][cc] = __builtin_elementwise_fma(lam2, Sa[r][cc], inner);
        }
        py = __builtin_fmaf(wf[r], ha, py);
      }
      if (lane == 0)
        part[((c * CH + tl) * B_ + g) * 256 + sub * 8 + wave] = py;
    }
    __syncthreads();
  }
}

__global__ void __launch_bounds__(512)
fb_final(const float* __restrict__ ws, const float* __restrict__ b_final,
         float* __restrict__ out) {
  const int wave = threadIdx.x >> 6, lane = threadIdx.x & 63;
  const int tb = blockIdx.x * 8 + wave;
  const float4 v = *(const float4*)(ws + HOFF + tb * 256 + lane * 4);
  const float s = dpp_wave_sum((v.x + v.y) + (v.z + v.w));
  if (lane == 0) out[tb] = sigmoid_f(s + b_final[0]);
}

// ================= launch =================

extern "C" void kernel_launch(void* const* d_in, const int* in_sizes, int n_in,
                              void* d_out, int out_size, void* d_ws,
                              size_t ws_size, hipStream_t stream) {
  const float* x       = (const float*)d_in[0];
  const float* w_mult  = (const float*)d_in[1];
  const float* b_mult  = (const float*)d_in[2];
  const float* w_add   = (const float*)d_in[3];
  const float* b_add   = (const float*)d_in[4];
  const float* w_final = (const float*)d_in[5];
  const float* b_final = (const float*)d_in[6];
  const float* p_lm    = (const float*)d_in[7];
  const float* p_la    = (const float*)d_in[8];
  const float* p_em    = (const float*)d_in[9];
  const float* p_ea    = (const float*)d_in[10];
  float* out = (float*)d_out;
  float* ws  = (float*)d_ws;

  if (ws_size >= WS_NEED) {
    hipLaunchKernelGGL(np_part1, dim3(256), dim3(512), 0, stream,
                       x, w_mult, b_mult, p_lm, p_em, ws);
    hipLaunchKernelGGL(np_mid, dim3(640), dim3(256), 0, stream,
                       w_add, b_add, p_la, p_ea, ws);
    hipLaunchKernelGGL(np_scan, dim3(64), dim3(512), 0, stream, ws);
    hipLaunchKernelGGL(np_final, dim3(128), dim3(512), 0, stream,
                       ws, w_final, b_final, out);
  } else {
    hipLaunchKernelGGL(fb_part1, dim3(256), dim3(512), 0, stream,
                       x, w_mult, b_mult, p_lm, p_em, ws);
    hipLaunchKernelGGL(fb_part2, dim3(256), dim3(512), 0, stream,
                       w_add, b_add, w_final, p_la, p_ea, ws);
    hipLaunchKernelGGL(fb_final, dim3(128), dim3(512), 0, stream,
                       ws, b_final, out);
  }
}